// Round 1
// baseline (1632.136 us; speedup 1.0000x reference)
//
#include <hip/hip_runtime.h>
#include <hip/hip_bf16.h>
#include <math.h>

// Problem constants (fixed by the reference file)
#define BB 2
#define NN 21760
#define CC 256
#define HH 8
#define LLV 4
#define KKP 4
#define DDIM 32
#define PP 21760
#define MROWS (BB * NN)   // 43520 query rows
#define VROWS (BB * PP)   // 43520 value rows

// ---------------------------------------------------------------------------
// Block-wide sum over 256 threads (4 waves of 64)
// ---------------------------------------------------------------------------
__device__ __forceinline__ float block_sum_256(float v, float* red) {
  #pragma unroll
  for (int o = 1; o < 64; o <<= 1) v += __shfl_xor(v, o, 64);
  int wid = threadIdx.x >> 6;
  int lane = threadIdx.x & 63;
  if (lane == 0) red[wid] = v;
  __syncthreads();
  float s = red[0] + red[1] + red[2] + red[3];
  __syncthreads();
  return s;
}

// ---------------------------------------------------------------------------
// Generic row-block projection: Y[m, j] = sum_k X[m,k] * W[k,j] + b[j]
// NCOL = 256, block = 256 threads, 8 rows per block
// ---------------------------------------------------------------------------
__global__ __launch_bounds__(256) void proj256(
    const float* __restrict__ X, const float* __restrict__ W,
    const float* __restrict__ bias, float* __restrict__ Y) {
  const int ROWS = 8;
  __shared__ float xs[ROWS][CC];
  int row0 = blockIdx.x * ROWS;
  int t = threadIdx.x;
  for (int i = t; i < ROWS * CC; i += 256) {
    xs[i >> 8][i & 255] = X[(size_t)(row0 + (i >> 8)) * CC + (i & 255)];
  }
  __syncthreads();
  float acc[ROWS] = {0.f, 0.f, 0.f, 0.f, 0.f, 0.f, 0.f, 0.f};
  for (int k = 0; k < CC; ++k) {
    float w = W[k * CC + t];
    #pragma unroll
    for (int r = 0; r < ROWS; ++r) acc[r] += xs[r][k] * w;
  }
  float bb = bias[t];
  #pragma unroll
  for (int r = 0; r < ROWS; ++r)
    Y[(size_t)(row0 + r) * CC + t] = acc[r] + bb;
}

// ---------------------------------------------------------------------------
// Attention-weight projection (N=128 cols) + per-16 softmax
// block = 128 threads, 8 rows per block
// ---------------------------------------------------------------------------
__global__ __launch_bounds__(128) void attn_proj_softmax(
    const float* __restrict__ Q, const float* __restrict__ W,
    const float* __restrict__ bias, float* __restrict__ AW) {
  const int ROWS = 8;
  __shared__ float xs[ROWS][CC];
  __shared__ float sl[ROWS][128];
  int row0 = blockIdx.x * ROWS;
  int t = threadIdx.x;
  for (int i = t; i < ROWS * CC; i += 128) {
    xs[i >> 8][i & 255] = Q[(size_t)(row0 + (i >> 8)) * CC + (i & 255)];
  }
  __syncthreads();
  float acc[ROWS] = {0.f, 0.f, 0.f, 0.f, 0.f, 0.f, 0.f, 0.f};
  for (int k = 0; k < CC; ++k) {
    float w = W[k * 128 + t];
    #pragma unroll
    for (int r = 0; r < ROWS; ++r) acc[r] += xs[r][k] * w;
  }
  float bb = bias[t];
  #pragma unroll
  for (int r = 0; r < ROWS; ++r) sl[r][t] = acc[r] + bb;
  __syncthreads();
  int g0 = t & ~15;  // start of this thread's group of 16
  #pragma unroll
  for (int r = 0; r < ROWS; ++r) {
    float mx = -1e30f;
    #pragma unroll
    for (int i = 0; i < 16; ++i) mx = fmaxf(mx, sl[r][g0 + i]);
    float sum = 0.f;
    #pragma unroll
    for (int i = 0; i < 16; ++i) sum += expf(sl[r][g0 + i] - mx);
    float y = expf(sl[r][t] - mx) / sum;
    AW[(size_t)(row0 + r) * 128 + t] = y;
  }
}

// ---------------------------------------------------------------------------
// Deformable sampling: one block per (b,n), thread t -> (h = t/32, d = t%32)
// ---------------------------------------------------------------------------
__device__ __forceinline__ float fetchv(const float* vb, int x, int y, int Wl, int Hl) {
  if (x < 0 || x >= Wl || y < 0 || y >= Hl) return 0.f;
  return vb[(size_t)(y * Wl + x) * (HH * DDIM)];
}

__global__ __launch_bounds__(256) void msda_sample(
    const float* __restrict__ value, const float* __restrict__ off,
    const float* __restrict__ aw, const float* __restrict__ refp,
    float* __restrict__ out) {
  int bn = blockIdx.x;               // 0 .. B*N-1
  int b = bn / NN;
  int t = threadIdx.x;
  __shared__ float s_off[256];
  __shared__ float s_aw[128];
  __shared__ float s_ref[8];
  s_off[t] = off[(size_t)bn * 256 + t];
  if (t < 128) s_aw[t] = aw[(size_t)bn * 128 + t];
  if (t < 8)  s_ref[t] = refp[(size_t)bn * 8 + t];
  __syncthreads();

  int h = t >> 5, d = t & 31;
  const int sz[4]  = {128, 64, 32, 16};
  const int st0[4] = {0, 16384, 20480, 21504};

  float acc = 0.f;
  #pragma unroll
  for (int l = 0; l < 4; ++l) {
    const int Wl = sz[l], Hl = sz[l];
    const float rx = s_ref[l * 2 + 0], ry = s_ref[l * 2 + 1];
    const float* vb = value + (((size_t)b * PP + st0[l]) * HH + h) * DDIM + d;
    #pragma unroll
    for (int k = 0; k < 4; ++k) {
      int idx = (h * 4 + l) * 4 + k;   // h*16 + l*4 + k
      float ox = s_off[idx * 2 + 0];
      float oy = s_off[idx * 2 + 1];
      float a  = s_aw[idx];
      float x = (rx + ox / (float)Wl) * (float)Wl - 0.5f;
      float y = (ry + oy / (float)Hl) * (float)Hl - 0.5f;
      float x0f = floorf(x), y0f = floorf(y);
      float wx = x - x0f, wy = y - y0f;
      int x0 = (int)x0f, y0 = (int)y0f;
      float v00 = fetchv(vb, x0,     y0,     Wl, Hl);
      float v10 = fetchv(vb, x0 + 1, y0,     Wl, Hl);
      float v01 = fetchv(vb, x0,     y0 + 1, Wl, Hl);
      float v11 = fetchv(vb, x0 + 1, y0 + 1, Wl, Hl);
      float s = v00 * (1.f - wx) * (1.f - wy) + v10 * wx * (1.f - wy)
              + v01 * (1.f - wx) * wy         + v11 * wx * wy;
      acc += a * s;
    }
  }
  out[(size_t)bn * 256 + t] = acc;
}

// ---------------------------------------------------------------------------
// Out-projection + 2q residual + LayerNorm1 -> x
// block = 256 threads, 8 rows
// ---------------------------------------------------------------------------
__global__ __launch_bounds__(256) void outproj_ln(
    const float* __restrict__ A, const float* __restrict__ Wo,
    const float* __restrict__ bo, const float* __restrict__ q,
    const float* __restrict__ g1, const float* __restrict__ be1,
    float* __restrict__ Xout) {
  const int ROWS = 8;
  __shared__ float as[ROWS][CC];
  __shared__ float red[4];
  int row0 = blockIdx.x * ROWS;
  int t = threadIdx.x;
  for (int i = t; i < ROWS * CC; i += 256) {
    as[i >> 8][i & 255] = A[(size_t)(row0 + (i >> 8)) * CC + (i & 255)];
  }
  __syncthreads();
  float acc[ROWS] = {0.f, 0.f, 0.f, 0.f, 0.f, 0.f, 0.f, 0.f};
  for (int k = 0; k < CC; ++k) {
    float w = Wo[k * CC + t];
    #pragma unroll
    for (int r = 0; r < ROWS; ++r) acc[r] += as[r][k] * w;
  }
  float bb = bo[t];
  float gg = g1[t], bbe = be1[t];
  for (int r = 0; r < ROWS; ++r) {
    float val = acc[r] + bb + 2.f * q[(size_t)(row0 + r) * CC + t];
    float m = block_sum_256(val, red) * (1.f / CC);
    float dv = val - m;
    float var = block_sum_256(dv * dv, red) * (1.f / CC);
    float o = dv * rsqrtf(var + 1e-5f) * gg + bbe;
    Xout[(size_t)(row0 + r) * CC + t] = o;
  }
}

// ---------------------------------------------------------------------------
// Fused FFN (relu(x@W1+b1)@W2+b2) + residual + LayerNorm2 -> out
// block = 256 threads, 8 rows; hidden (8x1024) kept in LDS
// ---------------------------------------------------------------------------
__global__ __launch_bounds__(256) void ffn_ln(
    const float* __restrict__ X, const float* __restrict__ W1,
    const float* __restrict__ b1, const float* __restrict__ W2,
    const float* __restrict__ b2, const float* __restrict__ g2,
    const float* __restrict__ be2, float* __restrict__ Out) {
  const int ROWS = 8;
  __shared__ float xs[ROWS][CC];        // 8 KB
  __shared__ float hs[ROWS][1024];      // 32 KB
  __shared__ float red[4];
  int row0 = blockIdx.x * ROWS;
  int t = threadIdx.x;
  for (int i = t; i < ROWS * CC; i += 256) {
    xs[i >> 8][i & 255] = X[(size_t)(row0 + (i >> 8)) * CC + (i & 255)];
  }
  __syncthreads();

  // Phase A: hidden = relu(x @ W1 + b1); thread t owns cols t, t+256, t+512, t+768
  float acc[4][ROWS];
  #pragma unroll
  for (int m = 0; m < 4; ++m)
    #pragma unroll
    for (int r = 0; r < ROWS; ++r) acc[m][r] = 0.f;
  for (int k = 0; k < CC; ++k) {
    float w0 = W1[(size_t)k * 1024 + t];
    float w1 = W1[(size_t)k * 1024 + t + 256];
    float w2 = W1[(size_t)k * 1024 + t + 512];
    float w3 = W1[(size_t)k * 1024 + t + 768];
    #pragma unroll
    for (int r = 0; r < ROWS; ++r) {
      float xv = xs[r][k];
      acc[0][r] += xv * w0;
      acc[1][r] += xv * w1;
      acc[2][r] += xv * w2;
      acc[3][r] += xv * w3;
    }
  }
  #pragma unroll
  for (int m = 0; m < 4; ++m) {
    float bm = b1[t + 256 * m];
    #pragma unroll
    for (int r = 0; r < ROWS; ++r)
      hs[r][t + 256 * m] = fmaxf(acc[m][r] + bm, 0.f);
  }
  __syncthreads();

  // Phase B: y = hidden @ W2 + b2; thread t owns output col t
  float acc2[ROWS] = {0.f, 0.f, 0.f, 0.f, 0.f, 0.f, 0.f, 0.f};
  for (int k = 0; k < 1024; ++k) {
    float w = W2[(size_t)k * 256 + t];
    #pragma unroll
    for (int r = 0; r < ROWS; ++r) acc2[r] += hs[r][k] * w;
  }
  float bb = b2[t];
  float gg = g2[t], bbe = be2[t];
  for (int r = 0; r < ROWS; ++r) {
    float val = acc2[r] + bb + xs[r][t];   // FFN + residual x
    float m = block_sum_256(val, red) * (1.f / CC);
    float dv = val - m;
    float var = block_sum_256(dv * dv, red) * (1.f / CC);
    float o = dv * rsqrtf(var + 1e-5f) * gg + bbe;
    Out[(size_t)(row0 + r) * CC + t] = o;
  }
}

// ---------------------------------------------------------------------------
// Launch
// ---------------------------------------------------------------------------
extern "C" void kernel_launch(void* const* d_in, const int* in_sizes, int n_in,
                              void* d_out, int out_size, void* d_ws, size_t ws_size,
                              hipStream_t stream) {
  const float* q     = (const float*)d_in[0];
  // d_in[1] = k (unused by the reference)
  const float* v     = (const float*)d_in[2];
  const float* refp  = (const float*)d_in[3];
  // d_in[4] = spatial_shapes, d_in[5] = start_levels (hardcoded constants)
  const float* W_off = (const float*)d_in[6];
  const float* b_off = (const float*)d_in[7];
  const float* W_at  = (const float*)d_in[8];
  const float* b_at  = (const float*)d_in[9];
  const float* W_val = (const float*)d_in[10];
  const float* b_val = (const float*)d_in[11];
  const float* W_out = (const float*)d_in[12];
  const float* b_out = (const float*)d_in[13];
  const float* W1    = (const float*)d_in[14];
  const float* b1    = (const float*)d_in[15];
  const float* W2    = (const float*)d_in[16];
  const float* b2    = (const float*)d_in[17];
  const float* g1    = (const float*)d_in[18];
  const float* be1   = (const float*)d_in[19];
  const float* g2    = (const float*)d_in[20];
  const float* be2   = (const float*)d_in[21];
  float* out = (float*)d_out;

  // Workspace layout (floats)
  float* ws    = (float*)d_ws;
  float* valb  = ws;                               // (B*P, 256) = 11,141,120
  float* offb  = valb + (size_t)VROWS * CC;        // (B*N, 256) = 11,141,120
  float* awb   = offb + (size_t)MROWS * CC;        // (B*N, 128) =  5,570,560
  float* msda  = awb  + (size_t)MROWS * 128;       // (B*N, 256) = 11,141,120
  float* xb    = valb;                             // alias: value dead after sampling

  const int rb = MROWS / 8;   // 5440 row-blocks

  // 1. value projection
  proj256<<<rb, 256, 0, stream>>>(v, W_val, b_val, valb);
  // 2. offset projection
  proj256<<<rb, 256, 0, stream>>>(q, W_off, b_off, offb);
  // 3. attention-weight projection + softmax
  attn_proj_softmax<<<rb, 128, 0, stream>>>(q, W_at, b_at, awb);
  // 4. deformable bilinear sampling
  msda_sample<<<MROWS, 256, 0, stream>>>(valb, offb, awb, refp, msda);
  // 5. out-projection + 2q residual + LN1
  outproj_ln<<<rb, 256, 0, stream>>>(msda, W_out, b_out, q, g1, be1, xb);
  // 6. fused FFN + residual + LN2
  ffn_ln<<<rb, 256, 0, stream>>>(xb, W1, b1, W2, b2, g2, be2, out);
}

// Round 2
// 1163.559 us; speedup vs baseline: 1.4027x; 1.4027x over previous
//
#include <hip/hip_runtime.h>
#include <hip/hip_bf16.h>
#include <math.h>

// Problem constants (fixed by the reference file)
#define BB 2
#define NN 21760
#define CC 256
#define HH 8
#define LLV 4
#define KKP 4
#define DDIM 32
#define PP 21760
#define MROWS (BB * NN)   // 43520 query rows
#define VROWS (BB * PP)   // 43520 value rows

typedef __attribute__((ext_vector_type(8))) short bf16x8;
typedef __attribute__((ext_vector_type(4))) float f32x4;

__device__ __forceinline__ unsigned short f2bf(float f) {
  unsigned u = __float_as_uint(f);
  u += 0x7fff + ((u >> 16) & 1);   // RNE
  return (unsigned short)(u >> 16);
}

// ---------------------------------------------------------------------------
// Block-wide sum over 256 threads (4 waves of 64)
// ---------------------------------------------------------------------------
__device__ __forceinline__ float block_sum_256(float v, float* red) {
  #pragma unroll
  for (int o = 1; o < 64; o <<= 1) v += __shfl_xor(v, o, 64);
  int wid = threadIdx.x >> 6;
  int lane = threadIdx.x & 63;
  if (lane == 0) red[wid] = v;
  __syncthreads();
  float s = red[0] + red[1] + red[2] + red[3];
  __syncthreads();
  return s;
}

// ---------------------------------------------------------------------------
// Generic row-block projection: Y[m, j] = sum_k X[m,k] * W[k,j] + b[j]
// ---------------------------------------------------------------------------
__global__ __launch_bounds__(256) void proj256(
    const float* __restrict__ X, const float* __restrict__ W,
    const float* __restrict__ bias, float* __restrict__ Y) {
  const int ROWS = 8;
  __shared__ float xs[ROWS][CC];
  int row0 = blockIdx.x * ROWS;
  int t = threadIdx.x;
  for (int i = t; i < ROWS * CC; i += 256) {
    xs[i >> 8][i & 255] = X[(size_t)(row0 + (i >> 8)) * CC + (i & 255)];
  }
  __syncthreads();
  float acc[ROWS] = {0.f, 0.f, 0.f, 0.f, 0.f, 0.f, 0.f, 0.f};
  for (int k = 0; k < CC; ++k) {
    float w = W[k * CC + t];
    #pragma unroll
    for (int r = 0; r < ROWS; ++r) acc[r] += xs[r][k] * w;
  }
  float bb = bias[t];
  #pragma unroll
  for (int r = 0; r < ROWS; ++r)
    Y[(size_t)(row0 + r) * CC + t] = acc[r] + bb;
}

// ---------------------------------------------------------------------------
// Attention-weight projection (N=128 cols) + per-16 softmax
// ---------------------------------------------------------------------------
__global__ __launch_bounds__(128) void attn_proj_softmax(
    const float* __restrict__ Q, const float* __restrict__ W,
    const float* __restrict__ bias, float* __restrict__ AW) {
  const int ROWS = 8;
  __shared__ float xs[ROWS][CC];
  __shared__ float sl[ROWS][128];
  int row0 = blockIdx.x * ROWS;
  int t = threadIdx.x;
  for (int i = t; i < ROWS * CC; i += 128) {
    xs[i >> 8][i & 255] = Q[(size_t)(row0 + (i >> 8)) * CC + (i & 255)];
  }
  __syncthreads();
  float acc[ROWS] = {0.f, 0.f, 0.f, 0.f, 0.f, 0.f, 0.f, 0.f};
  for (int k = 0; k < CC; ++k) {
    float w = W[k * 128 + t];
    #pragma unroll
    for (int r = 0; r < ROWS; ++r) acc[r] += xs[r][k] * w;
  }
  float bb = bias[t];
  #pragma unroll
  for (int r = 0; r < ROWS; ++r) sl[r][t] = acc[r] + bb;
  __syncthreads();
  int g0 = t & ~15;
  #pragma unroll
  for (int r = 0; r < ROWS; ++r) {
    float mx = -1e30f;
    #pragma unroll
    for (int i = 0; i < 16; ++i) mx = fmaxf(mx, sl[r][g0 + i]);
    float sum = 0.f;
    #pragma unroll
    for (int i = 0; i < 16; ++i) sum += expf(sl[r][g0 + i] - mx);
    float y = expf(sl[r][t] - mx) / sum;
    AW[(size_t)(row0 + r) * 128 + t] = y;
  }
}

// ---------------------------------------------------------------------------
// Deformable sampling: one block per (b,n), thread t -> (h = t/32, d = t%32)
// ---------------------------------------------------------------------------
__device__ __forceinline__ float fetchv(const float* vb, int x, int y, int Wl, int Hl) {
  if (x < 0 || x >= Wl || y < 0 || y >= Hl) return 0.f;
  return vb[(size_t)(y * Wl + x) * (HH * DDIM)];
}

__global__ __launch_bounds__(256) void msda_sample(
    const float* __restrict__ value, const float* __restrict__ off,
    const float* __restrict__ aw, const float* __restrict__ refp,
    float* __restrict__ out) {
  int bn = blockIdx.x;
  int b = bn / NN;
  int t = threadIdx.x;
  __shared__ float s_off[256];
  __shared__ float s_aw[128];
  __shared__ float s_ref[8];
  s_off[t] = off[(size_t)bn * 256 + t];
  if (t < 128) s_aw[t] = aw[(size_t)bn * 128 + t];
  if (t < 8)  s_ref[t] = refp[(size_t)bn * 8 + t];
  __syncthreads();

  int h = t >> 5, d = t & 31;
  const int sz[4]  = {128, 64, 32, 16};
  const int st0[4] = {0, 16384, 20480, 21504};

  float acc = 0.f;
  #pragma unroll
  for (int l = 0; l < 4; ++l) {
    const int Wl = sz[l], Hl = sz[l];
    const float rx = s_ref[l * 2 + 0], ry = s_ref[l * 2 + 1];
    const float* vb = value + (((size_t)b * PP + st0[l]) * HH + h) * DDIM + d;
    #pragma unroll
    for (int k = 0; k < 4; ++k) {
      int idx = (h * 4 + l) * 4 + k;
      float ox = s_off[idx * 2 + 0];
      float oy = s_off[idx * 2 + 1];
      float a  = s_aw[idx];
      float x = (rx + ox / (float)Wl) * (float)Wl - 0.5f;
      float y = (ry + oy / (float)Hl) * (float)Hl - 0.5f;
      float x0f = floorf(x), y0f = floorf(y);
      float wx = x - x0f, wy = y - y0f;
      int x0 = (int)x0f, y0 = (int)y0f;
      float v00 = fetchv(vb, x0,     y0,     Wl, Hl);
      float v10 = fetchv(vb, x0 + 1, y0,     Wl, Hl);
      float v01 = fetchv(vb, x0,     y0 + 1, Wl, Hl);
      float v11 = fetchv(vb, x0 + 1, y0 + 1, Wl, Hl);
      float s = v00 * (1.f - wx) * (1.f - wy) + v10 * wx * (1.f - wy)
              + v01 * (1.f - wx) * wy         + v11 * wx * wy;
      acc += a * s;
    }
  }
  out[(size_t)bn * 256 + t] = acc;
}

// ---------------------------------------------------------------------------
// Out-projection + 2q residual + LayerNorm1 -> x
// ---------------------------------------------------------------------------
__global__ __launch_bounds__(256) void outproj_ln(
    const float* __restrict__ A, const float* __restrict__ Wo,
    const float* __restrict__ bo, const float* __restrict__ q,
    const float* __restrict__ g1, const float* __restrict__ be1,
    float* __restrict__ Xout) {
  const int ROWS = 8;
  __shared__ float as[ROWS][CC];
  __shared__ float red[4];
  int row0 = blockIdx.x * ROWS;
  int t = threadIdx.x;
  for (int i = t; i < ROWS * CC; i += 256) {
    as[i >> 8][i & 255] = A[(size_t)(row0 + (i >> 8)) * CC + (i & 255)];
  }
  __syncthreads();
  float acc[ROWS] = {0.f, 0.f, 0.f, 0.f, 0.f, 0.f, 0.f, 0.f};
  for (int k = 0; k < CC; ++k) {
    float w = Wo[k * CC + t];
    #pragma unroll
    for (int r = 0; r < ROWS; ++r) acc[r] += as[r][k] * w;
  }
  float bb = bo[t];
  float gg = g1[t], bbe = be1[t];
  for (int r = 0; r < ROWS; ++r) {
    float val = acc[r] + bb + 2.f * q[(size_t)(row0 + r) * CC + t];
    float m = block_sum_256(val, red) * (1.f / CC);
    float dv = val - m;
    float var = block_sum_256(dv * dv, red) * (1.f / CC);
    float o = dv * rsqrtf(var + 1e-5f) * gg + bbe;
    Xout[(size_t)(row0 + r) * CC + t] = o;
  }
}

// ---------------------------------------------------------------------------
// Weight prep: W1[256][1024] -> W1T bf16 [1024][256];
//              W2[1024][256] -> W2T bf16 [256][1024]
// grid 1024 x 256 threads; i in [0, 262144)
// ---------------------------------------------------------------------------
__global__ __launch_bounds__(256) void prep_w(
    const float* __restrict__ W1, const float* __restrict__ W2,
    unsigned short* __restrict__ W1T, unsigned short* __restrict__ W2T) {
  int i = blockIdx.x * 256 + threadIdx.x;
  int n1 = i >> 8, k1 = i & 255;
  W1T[i] = f2bf(W1[(size_t)k1 * 1024 + n1]);
  int n2 = i >> 10, k2 = i & 1023;
  W2T[i] = f2bf(W2[(size_t)k2 * 256 + n2]);
}

// ---------------------------------------------------------------------------
// Fused FFN via bf16 MFMA + residual + LayerNorm2
// block = 256 threads (4 waves), M-tile = 16 rows
// LDS: xs 16x256 bf16 (swizzled, 8KB) + hs 16x1024 bf16 (swizzled, 32KB)
//      out_s 16x260 f32 aliases hs after GEMM2.
// Swizzle: byte ^= ((m&7)<<4)  -> conflict-free ds_read_b128 A-frags (T2/G4)
// ---------------------------------------------------------------------------
__global__ __launch_bounds__(256) void ffn_mfma(
    const float* __restrict__ X, const unsigned short* __restrict__ W1T,
    const float* __restrict__ b1, const unsigned short* __restrict__ W2T,
    const float* __restrict__ b2, const float* __restrict__ g2,
    const float* __restrict__ be2, float* __restrict__ Out) {
  __shared__ __align__(16) char smem[8192 + 32768];
  char* xs = smem;
  char* hs = smem + 8192;
  float* out_s = (float*)(smem + 8192);   // 16x260 f32 = 16640 B, aliases hs

  const int row0 = blockIdx.x * 16;
  const int t = threadIdx.x;
  const int w = t >> 6, lane = t & 63;
  const int c = lane & 15, kg = lane >> 4;

  // ---- stage X tile (fp32 global -> bf16 swizzled LDS) ----
  for (int i = t; i < 2048; i += 256) {
    int m = i >> 7;       // row 0..15
    int np = i & 127;     // pair of columns
    float2 xv = *(const float2*)(X + (size_t)(row0 + m) * 256 + np * 2);
    unsigned pk = (unsigned)f2bf(xv.x) | ((unsigned)f2bf(xv.y) << 16);
    int byte = (m * 512 + np * 4) ^ ((m & 7) << 4);
    *(unsigned*)(xs + byte) = pk;
  }
  __syncthreads();

  // ---- GEMM1: hid[16][1024] = relu(X @ W1 + b1); wave w owns n in [256w,256w+256) ----
  f32x4 acc1[16];
  #pragma unroll
  for (int nf = 0; nf < 16; ++nf) acc1[nf] = (f32x4){0.f, 0.f, 0.f, 0.f};
  for (int kc = 0; kc < 8; ++kc) {
    int abyte = (c * 512 + kc * 64 + kg * 16) ^ ((c & 7) << 4);
    bf16x8 a = *(const bf16x8*)(xs + abyte);
    const unsigned short* wp = W1T + (size_t)(w * 256) * 256 + kc * 32 + kg * 8;
    #pragma unroll
    for (int nf = 0; nf < 16; ++nf) {
      bf16x8 b = *(const bf16x8*)(wp + (size_t)(nf * 16 + c) * 256);
      acc1[nf] = __builtin_amdgcn_mfma_f32_16x16x32_bf16(a, b, acc1[nf], 0, 0, 0);
    }
  }
  // store hidden: relu(acc + b1) -> hs bf16, same XOR swizzle
  #pragma unroll
  for (int nf = 0; nf < 16; ++nf) {
    int n = w * 256 + nf * 16 + c;
    float bb = b1[n];
    #pragma unroll
    for (int i = 0; i < 4; ++i) {
      int m = kg * 4 + i;                    // C/D layout: row=(lane>>4)*4+reg
      float v = fmaxf(acc1[nf][i] + bb, 0.f);
      int byte = (m * 2048 + n * 2) ^ ((m & 7) << 4);
      *(unsigned short*)(hs + byte) = f2bf(v);
    }
  }
  __syncthreads();

  // ---- GEMM2: y[16][256] = hid @ W2; wave w owns n2 in [64w, 64w+64) ----
  f32x4 acc2[4];
  #pragma unroll
  for (int nf = 0; nf < 4; ++nf) acc2[nf] = (f32x4){0.f, 0.f, 0.f, 0.f};
  for (int kc = 0; kc < 32; ++kc) {
    int abyte = (c * 2048 + kc * 64 + kg * 16) ^ ((c & 7) << 4);
    bf16x8 a = *(const bf16x8*)(hs + abyte);
    const unsigned short* wp = W2T + (size_t)(w * 64) * 1024 + kc * 32 + kg * 8;
    #pragma unroll
    for (int nf = 0; nf < 4; ++nf) {
      bf16x8 b = *(const bf16x8*)(wp + (size_t)(nf * 16 + c) * 1024);
      acc2[nf] = __builtin_amdgcn_mfma_f32_16x16x32_bf16(a, b, acc2[nf], 0, 0, 0);
    }
  }
  __syncthreads();   // all hs reads complete before out_s overwrites it

  // ---- epilogue: + b2 + residual(X fp32) -> out_s ----
  #pragma unroll
  for (int nf = 0; nf < 4; ++nf) {
    int n2 = w * 64 + nf * 16 + c;
    float bb = b2[n2];
    #pragma unroll
    for (int i = 0; i < 4; ++i) {
      int m = kg * 4 + i;
      out_s[m * 260 + n2] = acc2[nf][i] + bb + X[(size_t)(row0 + m) * 256 + n2];
    }
  }
  __syncthreads();

  // ---- LayerNorm2 per row, one wave handles 4 rows ----
  float4 gv = *(const float4*)(g2 + lane * 4);
  float4 bev = *(const float4*)(be2 + lane * 4);
  for (int rr = 0; rr < 4; ++rr) {
    int r = w * 4 + rr;
    float4 v = *(const float4*)(out_s + r * 260 + lane * 4);
    float s = v.x + v.y + v.z + v.w;
    float s2 = v.x * v.x + v.y * v.y + v.z * v.z + v.w * v.w;
    #pragma unroll
    for (int o = 1; o < 64; o <<= 1) {
      s += __shfl_xor(s, o, 64);
      s2 += __shfl_xor(s2, o, 64);
    }
    float mean = s * (1.f / 256.f);
    float var = s2 * (1.f / 256.f) - mean * mean;
    float rstd = rsqrtf(var + 1e-5f);
    float4 o4;
    o4.x = (v.x - mean) * rstd * gv.x + bev.x;
    o4.y = (v.y - mean) * rstd * gv.y + bev.y;
    o4.z = (v.z - mean) * rstd * gv.z + bev.z;
    o4.w = (v.w - mean) * rstd * gv.w + bev.w;
    *(float4*)(Out + (size_t)(row0 + r) * 256 + lane * 4) = o4;
  }
}

// ---------------------------------------------------------------------------
// Launch
// ---------------------------------------------------------------------------
extern "C" void kernel_launch(void* const* d_in, const int* in_sizes, int n_in,
                              void* d_out, int out_size, void* d_ws, size_t ws_size,
                              hipStream_t stream) {
  const float* q     = (const float*)d_in[0];
  const float* v     = (const float*)d_in[2];
  const float* refp  = (const float*)d_in[3];
  const float* W_off = (const float*)d_in[6];
  const float* b_off = (const float*)d_in[7];
  const float* W_at  = (const float*)d_in[8];
  const float* b_at  = (const float*)d_in[9];
  const float* W_val = (const float*)d_in[10];
  const float* b_val = (const float*)d_in[11];
  const float* W_out = (const float*)d_in[12];
  const float* b_out = (const float*)d_in[13];
  const float* W1    = (const float*)d_in[14];
  const float* b1    = (const float*)d_in[15];
  const float* W2    = (const float*)d_in[16];
  const float* b2    = (const float*)d_in[17];
  const float* g1    = (const float*)d_in[18];
  const float* be1   = (const float*)d_in[19];
  const float* g2    = (const float*)d_in[20];
  const float* be2   = (const float*)d_in[21];
  float* out = (float*)d_out;

  // Workspace layout (floats)
  float* ws    = (float*)d_ws;
  float* valb  = ws;                               // (B*P, 256)
  float* offb  = valb + (size_t)VROWS * CC;        // (B*N, 256)
  float* awb   = offb + (size_t)MROWS * CC;        // (B*N, 128)
  float* msda  = awb  + (size_t)MROWS * 128;       // (B*N, 256)
  float* xb    = valb;                             // alias: value dead after sampling
  // bf16 weights live in offb region (dead after msda_sample)
  unsigned short* W1T = (unsigned short*)offb;     // 1024x256 bf16
  unsigned short* W2T = W1T + 262144;              // 256x1024 bf16

  const int rb = MROWS / 8;    // 5440
  const int mb = MROWS / 16;   // 2720

  proj256<<<rb, 256, 0, stream>>>(v, W_val, b_val, valb);
  proj256<<<rb, 256, 0, stream>>>(q, W_off, b_off, offb);
  attn_proj_softmax<<<rb, 128, 0, stream>>>(q, W_at, b_at, awb);
  msda_sample<<<MROWS, 256, 0, stream>>>(valb, offb, awb, refp, msda);
  prep_w<<<1024, 256, 0, stream>>>(W1, W2, W1T, W2T);          // offb now dead
  outproj_ln<<<rb, 256, 0, stream>>>(msda, W_out, b_out, q, g1, be1, xb);
  ffn_mfma<<<mb, 256, 0, stream>>>(xb, W1T, b1, W2T, b2, g2, be2, out);
}